// Round 2
// baseline (364.114 us; speedup 1.0000x reference)
//
#include <hip/hip_runtime.h>
#include <math.h>

#define B_ 8
#define L_ 336
#define H_ 192
#define C_ 321
#define K_ 16
#define S_ 8
#define H2_ 97
#define OUT_ 3201
#define SEQLEN_ 528
#define BC_ (B_ * C_)
#define JD_ 136
#define MIXJ_ 291

typedef float v2f __attribute__((ext_vector_type(2)));
typedef float v4f __attribute__((ext_vector_type(4)));

static constexpr size_t OFF_SEQ  = 0;
static constexpr size_t OFF_MU   = OFF_SEQ + (size_t)BC_ * SEQLEN_;
static constexpr size_t OFF_STD  = OFF_MU + BC_;
static constexpr size_t OFF_P    = OFF_STD + BC_;
static constexpr size_t OFF_CF   = OFF_P + (size_t)BC_ * S_;
static constexpr size_t OFF_W2   = OFF_CF + (size_t)BC_ * K_;
static constexpr size_t OFF_WT2  = (OFF_W2 + (size_t)JD_ * OUT_ + 1) & ~(size_t)1;
static constexpr size_t OFF_FILT = OFF_WT2 + (size_t)2 * MIXJ_ * H2_;

#define TWO_PI_F 6.283185307179586f
#define CT_ 32   // c-tile for kPre

// ---------------------------------------------------------------------------
// kPre: fused instance-norm stats + cls softmax + corr_feat + normalized seq
// transpose.  Block = (b, 32-c tile), 256 threads: i = tid&31 (c lane),
// j = tid>>5 (l chunk).  All global loads coalesced over c; seq written
// through an LDS transpose tile so writes are coalesced over t.
// ---------------------------------------------------------------------------
__launch_bounds__(256)
__global__ void kPre(const float* __restrict__ x, const float* __restrict__ y_hat,
                     const float* __restrict__ cls_w, const float* __restrict__ cls_bias,
                     const float* __restrict__ basic_state, const float* __restrict__ r,
                     const float* __restrict__ temperature,
                     float* __restrict__ mu, float* __restrict__ stdv,
                     float* __restrict__ p, float* __restrict__ cf,
                     float* __restrict__ seq) {
  __shared__ float part[8][10][CT_];   // [lchunk][{sum,sumsq,cls0..7}][c]
  __shared__ float smu[CT_], sistd[CT_];
  __shared__ float tile[CT_][68];

  int b = blockIdx.x;
  int cb = blockIdx.y * CT_;
  int i = threadIdx.x & (CT_ - 1);
  int j = threadIdx.x >> 5;
  int c = cb + i;
  bool cok = c < C_;

  float sum = 0.f, sumsq = 0.f;
  float a[S_];
#pragma unroll
  for (int s = 0; s < S_; s++) a[s] = 0.f;

  if (cok) {
    for (int l = j; l < L_; l += 8) {
      float v = x[((size_t)b * L_ + l) * C_ + c];
      sum += v;
      sumsq = fmaf(v, v, sumsq);
#pragma unroll
      for (int s = 0; s < S_; s++) a[s] = fmaf(v, cls_w[s * L_ + l], a[s]);
    }
  }
  part[j][0][i] = sum;
  part[j][1][i] = sumsq;
#pragma unroll
  for (int s = 0; s < S_; s++) part[j][2 + s][i] = a[s];
  __syncthreads();

  if (threadIdx.x < CT_ && cok) {
    float s0 = 0.f, s1 = 0.f, ac[S_];
#pragma unroll
    for (int s = 0; s < S_; s++) ac[s] = 0.f;
    for (int jj = 0; jj < 8; jj++) {
      s0 += part[jj][0][i];
      s1 += part[jj][1][i];
#pragma unroll
      for (int s = 0; s < S_; s++) ac[s] += part[jj][2 + s][i];
    }
    float m = s0 * (1.f / L_);
    float var = fmaxf(s1 * (1.f / L_) - m * m, 0.f);
    float sd = sqrtf(var + 1e-8f);
    float is = 1.f / sd;
    int bc = b * C_ + c;
    mu[bc] = m;
    stdv[bc] = sd;
    smu[i] = m;
    sistd[i] = is;

    // p softmax
    float lg[S_], mx = -1e30f;
#pragma unroll
    for (int s = 0; s < S_; s++) {
      lg[s] = ac[s] + cls_bias[s] + basic_state[c * S_ + s];
      mx = fmaxf(mx, lg[s]);
    }
    float den = 0.f;
#pragma unroll
    for (int s = 0; s < S_; s++) { float e = expf(lg[s] - mx); lg[s] = e; den += e; }
    float iden = 1.f / den;
#pragma unroll
    for (int s = 0; s < S_; s++) p[(size_t)bc * S_ + s] = lg[s] * iden;

    // corr_feat
    float it = 1.f / temperature[0];
    float aa[K_], am = it;
#pragma unroll
    for (int k = 0; k < K_; k++) {
      aa[k] = fabsf(r[(size_t)bc * K_ + k]) * it;
      am = fmaxf(am, aa[k]);
    }
    float den2 = expf(it - am);
#pragma unroll
    for (int k = 0; k < K_; k++) { float e = expf(aa[k] - am); aa[k] = e; den2 += e; }
    float iden2 = 1.f / den2;
#pragma unroll
    for (int k = 0; k < K_; k++) cf[(size_t)bc * K_ + k] = aa[k] * iden2;
  }
  __syncthreads();

  // transpose + normalize into seq, 8 tiles of 66 t-values
  for (int t0 = 0; t0 < SEQLEN_; t0 += 66) {
    for (int m = 0;; m++) {
      int tt = j + 8 * m;
      if (tt >= 66) break;
      int t = t0 + tt;
      float v = 0.f;
      if (cok) {
        v = (t < L_) ? x[((size_t)b * L_ + t) * C_ + c]
                     : y_hat[((size_t)b * H_ + (t - L_)) * C_ + c];
        v = (v - smu[i]) * sistd[i];
      }
      tile[i][tt] = v;
    }
    __syncthreads();
    // wave j (8 waves of 32 within 256 threads -> use tid>>5 groups of 32)
    {
      int lane = threadIdx.x & 31;
      int grp = threadIdx.x >> 5;   // 8 groups, each handles 4 rows
#pragma unroll
      for (int rr = 0; rr < 4; rr++) {
        int ri = grp * 4 + rr;
        int cc2 = cb + ri;
        if (cc2 < C_) {
          float* dst = seq + ((size_t)b * C_ + cc2) * SEQLEN_ + t0;
          for (int pass = 0; pass < 3; pass++) {
            int tt = lane + 32 * pass;
            if (tt < 66) dst[tt] = tile[ri][tt];
          }
        }
      }
    }
    __syncthreads();
  }
}

// ---------------------------------------------------------------------------
// kPackW2: W2[j][o], j = s*17 + t  (t<16: mh_w[s, t*OUT+o]; t=16: mh_b)
// ---------------------------------------------------------------------------
__global__ void kPackW2(const float* __restrict__ mh_w, const float* __restrict__ mh_b,
                        float* __restrict__ W2) {
  int idx = blockIdx.x * blockDim.x + threadIdx.x;
  if (idx >= JD_ * OUT_) return;
  int j = idx / OUT_;
  int o = idx - j * OUT_;
  int s = j / 17;
  int t = j - s * 17;
  W2[idx] = (t < K_) ? mh_w[(size_t)s * (K_ * OUT_) + (size_t)t * OUT_ + o]
                     : mh_b[(size_t)s * OUT_ + o];
}

// ---------------------------------------------------------------------------
// kPackMixW: wT2[j*97+g] = (wr[g,j], wi[g,j])
// ---------------------------------------------------------------------------
__global__ void kPackMixW(const float* __restrict__ mwr, const float* __restrict__ mwi,
                          float2* __restrict__ wT2) {
  int idx = blockIdx.x * blockDim.x + threadIdx.x;
  if (idx >= MIXJ_ * H2_) return;
  int j = idx / H2_;
  int g = idx - j * H2_;
  wT2[idx] = make_float2(mwr[(size_t)g * MIXJ_ + j], mwi[(size_t)g * MIXJ_ + j]);
}

// ---------------------------------------------------------------------------
// kFilt: filt[row][o] = sum_j u[row][j] * W2[j][o];  Mtile=32, Ntile=256
// ---------------------------------------------------------------------------
__launch_bounds__(256)
__global__ void kFilt(const float* __restrict__ p, const float* __restrict__ cf,
                      const float* __restrict__ W2, float* __restrict__ filt) {
  __shared__ __align__(16) float u[32][140];
  int rowBase = blockIdx.y * 32;
  for (int i = threadIdx.x; i < 32 * JD_; i += 256) {
    int m = i / JD_;
    int j = i - m * JD_;
    int row = rowBase + m;
    float v = 0.f;
    if (row < BC_) {
      int s = j / 17;
      int t = j - s * 17;
      float ps = p[(size_t)row * S_ + s];
      v = (t < K_) ? ps * cf[(size_t)row * K_ + t] : ps;
    }
    u[m][j] = v;
  }
  __syncthreads();

  int o = blockIdx.x * 256 + threadIdx.x;
  if (o >= OUT_) return;
  float accv[32];
#pragma unroll
  for (int m = 0; m < 32; m++) accv[m] = 0.f;

  for (int jq = 0; jq < JD_ / 4; jq++) {
    int j = jq * 4;
    float w0 = W2[(size_t)(j + 0) * OUT_ + o];
    float w1 = W2[(size_t)(j + 1) * OUT_ + o];
    float w2 = W2[(size_t)(j + 2) * OUT_ + o];
    float w3 = W2[(size_t)(j + 3) * OUT_ + o];
#pragma unroll
    for (int m = 0; m < 32; m++) {
      float4 uv = *reinterpret_cast<const float4*>(&u[m][j]);
      accv[m] = fmaf(uv.x, w0, fmaf(uv.y, w1, fmaf(uv.z, w2, fmaf(uv.w, w3, accv[m]))));
    }
  }
#pragma unroll
  for (int m = 0; m < 32; m++) {
    int row = rowBase + m;
    if (row < BC_) filt[(size_t)row * OUT_ + o] = accv[m];
  }
}

// ---------------------------------------------------------------------------
// kMain: 256 threads/block, 1 block per (b,c).
// part = tid>>7 (0 = real, 1 = imag), f = tid&127 (active f<97).
// DFT inner loop in v2f arithmetic (v_pk_fma_f32 eligible).
// ---------------------------------------------------------------------------
__launch_bounds__(256)
__global__ void kMain(const float* __restrict__ seq, const float* __restrict__ mu,
                      const float* __restrict__ stdv, const float* __restrict__ filt,
                      const int* __restrict__ lead, const int* __restrict__ shiftv,
                      const float* __restrict__ r, const float2* __restrict__ wT2,
                      const float* __restrict__ mbr, const float* __restrict__ mbi,
                      float* __restrict__ out) {
  __shared__ __align__(16) v4f rows4[17][48];   // rows[17][192]
  __shared__ float mixr[MIXJ_];
  __shared__ float mixi[MIXJ_];
  __shared__ float zr_s[H2_];
  __shared__ float zi_s[H2_];

  int bc = blockIdx.x;
  int b = bc / C_;
  int c = bc - b * C_;
  int tid = threadIdx.x;

  // phase 1: gather leader windows + own yhn into LDS
#pragma unroll 1
  for (int k = 0; k < 17; k++) {
    float sg;
    const float* src;
    if (k < K_) {
      int ld = lead[(size_t)bc * K_ + k];
      int sh = shiftv[(size_t)bc * K_ + k];
      float rv = r[(size_t)bc * K_ + k];
      sg = (rv > 0.f) ? 1.f : ((rv < 0.f) ? -1.f : 0.f);
      src = seq + ((size_t)b * C_ + ld) * SEQLEN_ + (L_ - sh);
    } else {
      sg = 1.f;
      src = seq + (size_t)bc * SEQLEN_ + L_;
    }
    if (tid < H_) ((float*)rows4[k])[tid] = src[tid] * sg;
  }
  __syncthreads();

  int part = tid >> 7;     // 0: real, 1: imag
  int f = tid & 127;
  float aX[17];

  if (f < H2_) {
    // phase 2: DFT, packed-f32 inner loop
    v2f acc[17];
#pragma unroll
    for (int k = 0; k < 17; k++) acc[k] = (v2f){0.f, 0.f};

    float ang = -(TWO_PI_F / 192.f) * (float)f;
    float cc1, ss1, cc2, ss2, cc3, ss3, cc4, ss4;
    sincosf(ang, &ss1, &cc1);
    sincosf(2.f * ang, &ss2, &cc2);
    sincosf(3.f * ang, &ss3, &cc3);
    sincosf(4.f * ang, &ss4, &cc4);

    v2f A0, B0, A1, B1;
    if (part == 0) {
      A0 = (v2f){1.f, cc1};  B0 = (v2f){0.f, -ss1};
      A1 = (v2f){cc2, cc3};  B1 = (v2f){-ss2, -ss3};
    } else {
      A0 = (v2f){0.f, ss1};  B0 = (v2f){1.f, cc1};
      A1 = (v2f){ss2, ss3};  B1 = (v2f){cc2, cc3};
    }

    float cr = 1.f, ci = 0.f;
    for (int hq = 0; hq < 48; hq++) {
      v2f d0 = cr * A0 + ci * B0;
      v2f d1 = cr * A1 + ci * B1;
      float nr = cr * cc4 - ci * ss4;
      float ni = cr * ss4 + ci * cc4;
#pragma unroll
      for (int k = 0; k < 17; k++) {
        v4f v = rows4[k][hq];
        v2f lo = __builtin_shufflevector(v, v, 0, 1);
        v2f hi = __builtin_shufflevector(v, v, 2, 3);
        acc[k] += lo * d0 + hi * d1;
      }
      cr = nr; ci = ni;
    }
#pragma unroll
    for (int k = 0; k < 17; k++) aX[k] = acc[k].x + acc[k].y;

    // phase 3: filt combine (each half computes its own part)
    const float* fb = filt + (size_t)bc * OUT_ + f;
    float yf = aX[16];
    float S1 = 0.f, S2 = 0.f, sg2 = 0.f;
#pragma unroll
    for (int k = 0; k < K_; k++) {
      float g1 = fb[k * H2_];
      float g2 = fb[(K_ + k) * H2_];
      S1 = fmaf(aX[k], g1, S1);
      S2 = fmaf(aX[k], g1 * g2, S2);
      sg2 += g2;
    }
    S2 = fmaf(-yf, sg2, S2);
    float g3 = fb[32 * H2_];
    float* mx = part ? mixi : mixr;
    mx[f] = S1;
    mx[H2_ + f] = S2;
    mx[2 * H2_ + f] = yf * g3;
  }
  __syncthreads();

  // phase 4: complex mix matmul (part computes Re or Im of z[f])
  if (f < H2_) {
    float z = part ? mbi[f] : mbr[f];
    if (part == 0) {
      for (int j = 0; j < MIXJ_; j++) {
        float2 w = wT2[(size_t)j * H2_ + f];
        z = fmaf(mixr[j], w.x, fmaf(-mixi[j], w.y, z));
      }
      zr_s[f] = z;
    } else {
      for (int j = 0; j < MIXJ_; j++) {
        float2 w = wT2[(size_t)j * H2_ + f];
        z = fmaf(mixr[j], w.y, fmaf(mixi[j], w.x, z));
      }
      zi_s[f] = z;
    }
  }
  __syncthreads();

  // phase 5: irfft + epilogue (thread = h)
  if (tid < H_) {
    int h = tid;
    float m = mu[bc], sd = stdv[bc];
    float ang = (TWO_PI_F / 192.f) * (float)h;
    float cs, sn;
    sincosf(ang, &sn, &cs);
    float acc = 0.5f * zr_s[0] + ((h & 1) ? -0.5f : 0.5f) * zr_s[96];
    float cv = 1.f, sv = 0.f;
    for (int fq = 1; fq < 96; fq++) {
      float nc = cv * cs - sv * sn;
      float ns = cv * sn + sv * cs;
      cv = nc; sv = ns;
      acc = fmaf(zr_s[fq], cv, fmaf(-zi_s[fq], sv, acc));
    }
    float yv = acc * (2.f / 192.f);
    float yhnv = ((const float*)rows4[16])[h];
    out[((size_t)b * H_ + h) * C_ + c] = fmaf(yhnv + yv, sd, m);
  }
}

// ---------------------------------------------------------------------------
extern "C" void kernel_launch(void* const* d_in, const int* in_sizes, int n_in,
                              void* d_out, int out_size, void* d_ws, size_t ws_size,
                              hipStream_t stream) {
  const float* x           = (const float*)d_in[0];
  const float* y_hat       = (const float*)d_in[1];
  const int*   lead        = (const int*)d_in[2];
  const int*   shiftv      = (const int*)d_in[3];
  const float* r           = (const float*)d_in[4];
  const float* temperature = (const float*)d_in[5];
  const float* cls_w       = (const float*)d_in[6];
  const float* cls_bias    = (const float*)d_in[7];
  const float* basic_state = (const float*)d_in[8];
  const float* mh_w        = (const float*)d_in[9];
  const float* mh_b        = (const float*)d_in[10];
  const float* mwr         = (const float*)d_in[11];
  const float* mwi         = (const float*)d_in[12];
  const float* mbr         = (const float*)d_in[13];
  const float* mbi         = (const float*)d_in[14];
  float* out = (float*)d_out;
  float* ws  = (float*)d_ws;

  dim3 gPre(B_, (C_ + CT_ - 1) / CT_);
  kPre<<<gPre, 256, 0, stream>>>(x, y_hat, cls_w, cls_bias, basic_state, r,
                                 temperature, ws + OFF_MU, ws + OFF_STD,
                                 ws + OFF_P, ws + OFF_CF, ws + OFF_SEQ);

  kPackW2<<<(JD_ * OUT_ + 255) / 256, 256, 0, stream>>>(mh_w, mh_b, ws + OFF_W2);

  kPackMixW<<<(MIXJ_ * H2_ + 255) / 256, 256, 0, stream>>>(
      mwr, mwi, (float2*)(ws + OFF_WT2));

  dim3 gF((OUT_ + 255) / 256, (BC_ + 31) / 32);
  kFilt<<<gF, 256, 0, stream>>>(ws + OFF_P, ws + OFF_CF, ws + OFF_W2, ws + OFF_FILT);

  kMain<<<BC_, 256, 0, stream>>>(ws + OFF_SEQ, ws + OFF_MU, ws + OFF_STD,
                                 ws + OFF_FILT, lead, shiftv, r,
                                 (const float2*)(ws + OFF_WT2), mbr, mbi, out);
}

// Round 4
// 337.603 us; speedup vs baseline: 1.0785x; 1.0785x over previous
//
#include <hip/hip_runtime.h>
#include <math.h>

#define B_ 8
#define L_ 336
#define H_ 192
#define C_ 321
#define K_ 16
#define S_ 8
#define H2_ 97
#define OUT_ 3201
#define SEQLEN_ 528
#define BC_ (B_ * C_)
#define JD_ 136
#define MIXJ_ 291

typedef float v2f __attribute__((ext_vector_type(2)));
typedef float v4f __attribute__((ext_vector_type(4)));

static constexpr size_t OFF_SEQ  = 0;
static constexpr size_t OFF_MU   = OFF_SEQ + (size_t)BC_ * SEQLEN_;
static constexpr size_t OFF_STD  = OFF_MU + BC_;
static constexpr size_t OFF_P    = OFF_STD + BC_;
static constexpr size_t OFF_CF   = OFF_P + (size_t)BC_ * S_;
static constexpr size_t OFF_U    = OFF_CF + (size_t)BC_ * K_;
static constexpr size_t OFF_WT2  = (OFF_U + (size_t)BC_ * JD_ + 1) & ~(size_t)1;
static constexpr size_t OFF_FILT = OFF_WT2 + (size_t)2 * MIXJ_ * H2_;

#define TWO_PI_F 6.283185307179586f
#define CT_ 32   // c-tile for kPre

// ---------------------------------------------------------------------------
// kPre: fused instance-norm stats + cls softmax + corr_feat + normalized seq
// transpose (unchanged from round 2 — it worked).
// ---------------------------------------------------------------------------
__launch_bounds__(256)
__global__ void kPre(const float* __restrict__ x, const float* __restrict__ y_hat,
                     const float* __restrict__ cls_w, const float* __restrict__ cls_bias,
                     const float* __restrict__ basic_state, const float* __restrict__ r,
                     const float* __restrict__ temperature,
                     float* __restrict__ mu, float* __restrict__ stdv,
                     float* __restrict__ p, float* __restrict__ cf,
                     float* __restrict__ seq) {
  __shared__ float part[8][10][CT_];
  __shared__ float smu[CT_], sistd[CT_];
  __shared__ float tile[CT_][68];

  int b = blockIdx.x;
  int cb = blockIdx.y * CT_;
  int i = threadIdx.x & (CT_ - 1);
  int j = threadIdx.x >> 5;
  int c = cb + i;
  bool cok = c < C_;

  float sum = 0.f, sumsq = 0.f;
  float a[S_];
#pragma unroll
  for (int s = 0; s < S_; s++) a[s] = 0.f;

  if (cok) {
    for (int l = j; l < L_; l += 8) {
      float v = x[((size_t)b * L_ + l) * C_ + c];
      sum += v;
      sumsq = fmaf(v, v, sumsq);
#pragma unroll
      for (int s = 0; s < S_; s++) a[s] = fmaf(v, cls_w[s * L_ + l], a[s]);
    }
  }
  part[j][0][i] = sum;
  part[j][1][i] = sumsq;
#pragma unroll
  for (int s = 0; s < S_; s++) part[j][2 + s][i] = a[s];
  __syncthreads();

  if (threadIdx.x < CT_ && cok) {
    float s0 = 0.f, s1 = 0.f, ac[S_];
#pragma unroll
    for (int s = 0; s < S_; s++) ac[s] = 0.f;
    for (int jj = 0; jj < 8; jj++) {
      s0 += part[jj][0][i];
      s1 += part[jj][1][i];
#pragma unroll
      for (int s = 0; s < S_; s++) ac[s] += part[jj][2 + s][i];
    }
    float m = s0 * (1.f / L_);
    float var = fmaxf(s1 * (1.f / L_) - m * m, 0.f);
    float sd = sqrtf(var + 1e-8f);
    float is = 1.f / sd;
    int bc = b * C_ + c;
    mu[bc] = m;
    stdv[bc] = sd;
    smu[i] = m;
    sistd[i] = is;

    float lg[S_], mx = -1e30f;
#pragma unroll
    for (int s = 0; s < S_; s++) {
      lg[s] = ac[s] + cls_bias[s] + basic_state[c * S_ + s];
      mx = fmaxf(mx, lg[s]);
    }
    float den = 0.f;
#pragma unroll
    for (int s = 0; s < S_; s++) { float e = expf(lg[s] - mx); lg[s] = e; den += e; }
    float iden = 1.f / den;
#pragma unroll
    for (int s = 0; s < S_; s++) p[(size_t)bc * S_ + s] = lg[s] * iden;

    float it = 1.f / temperature[0];
    float aa[K_], am = it;
#pragma unroll
    for (int k = 0; k < K_; k++) {
      aa[k] = fabsf(r[(size_t)bc * K_ + k]) * it;
      am = fmaxf(am, aa[k]);
    }
    float den2 = expf(it - am);
#pragma unroll
    for (int k = 0; k < K_; k++) { float e = expf(aa[k] - am); aa[k] = e; den2 += e; }
    float iden2 = 1.f / den2;
#pragma unroll
    for (int k = 0; k < K_; k++) cf[(size_t)bc * K_ + k] = aa[k] * iden2;
  }
  __syncthreads();

  for (int t0 = 0; t0 < SEQLEN_; t0 += 66) {
    for (int m = 0;; m++) {
      int tt = j + 8 * m;
      if (tt >= 66) break;
      int t = t0 + tt;
      float v = 0.f;
      if (cok) {
        v = (t < L_) ? x[((size_t)b * L_ + t) * C_ + c]
                     : y_hat[((size_t)b * H_ + (t - L_)) * C_ + c];
        v = (v - smu[i]) * sistd[i];
      }
      tile[i][tt] = v;
    }
    __syncthreads();
    {
      int lane = threadIdx.x & 31;
      int grp = threadIdx.x >> 5;
#pragma unroll
      for (int rr = 0; rr < 4; rr++) {
        int ri = grp * 4 + rr;
        int cc2 = cb + ri;
        if (cc2 < C_) {
          float* dst = seq + ((size_t)b * C_ + cc2) * SEQLEN_ + t0;
          for (int pass = 0; pass < 3; pass++) {
            int tt = lane + 32 * pass;
            if (tt < 66) dst[tt] = tile[ri][tt];
          }
        }
      }
    }
    __syncthreads();
  }
}

// ---------------------------------------------------------------------------
// kU: u[bc][j] = p[bc][s(j)] * (t(j)<16 ? cf[bc][t(j)] : 1)
// ---------------------------------------------------------------------------
__global__ void kU(const float* __restrict__ p, const float* __restrict__ cf,
                   float* __restrict__ U) {
  int idx = blockIdx.x * 256 + threadIdx.x;
  if (idx >= BC_ * JD_) return;
  int bc = idx / JD_;
  int j = idx - bc * JD_;
  int s = j / 17;
  int t = j - s * 17;
  float v = p[(size_t)bc * S_ + s];
  if (t < K_) v *= cf[(size_t)bc * K_ + t];
  U[idx] = v;
}

// ---------------------------------------------------------------------------
// kPackMixW: wT2[j*97+g] = (wr[g,j], wi[g,j])
// ---------------------------------------------------------------------------
__global__ void kPackMixW(const float* __restrict__ mwr, const float* __restrict__ mwi,
                          float2* __restrict__ wT2) {
  int idx = blockIdx.x * blockDim.x + threadIdx.x;
  if (idx >= MIXJ_ * H2_) return;
  int j = idx / H2_;
  int g = idx - j * H2_;
  wT2[idx] = make_float2(mwr[(size_t)g * MIXJ_ + j], mwi[(size_t)g * MIXJ_ + j]);
}

// ---------------------------------------------------------------------------
// kFilt: SGPR-broadcast GEMM.  Thread = one o-column; W2 column (virtual,
// j = s*17+t -> mh_w/mh_b) held in 136 VGPRs; u[m][j] read via wave-uniform
// s_load (SGPR operand of v_fma).  No LDS.  Coalesced stores.
// ---------------------------------------------------------------------------
__launch_bounds__(256)
__global__ void kFilt(const float* __restrict__ U, const float* __restrict__ mh_w,
                      const float* __restrict__ mh_b, float* __restrict__ filt) {
  int o = blockIdx.x * 256 + threadIdx.x;
  bool ook = o < OUT_;
  int oc = ook ? o : (OUT_ - 1);

  float w[JD_];
#pragma unroll
  for (int s = 0; s < S_; s++) {
#pragma unroll
    for (int t = 0; t < 17; t++) {
      w[s * 17 + t] = (t < K_)
          ? mh_w[(size_t)s * (K_ * OUT_) + (size_t)t * OUT_ + oc]
          : mh_b[(size_t)s * OUT_ + oc];
    }
  }

  int mBase = blockIdx.y * 64;
#pragma unroll 1
  for (int mi = 0; mi < 64; mi++) {
    int m = mBase + mi;
    if (m >= BC_) break;
    const float* up = U + (size_t)m * JD_;   // wave-uniform address -> s_load
    float acc = 0.f;
#pragma unroll
    for (int j = 0; j < JD_; j++) acc = fmaf(up[j], w[j], acc);
    if (ook) filt[(size_t)m * OUT_ + o] = acc;
  }
}

// ---------------------------------------------------------------------------
// kMain: ONE WAVE (64 threads) per (b,c).
// Lane t<49 handles f=t and f2=96-t via even/odd-h accumulators:
//   F(f)  = (e.x+o.x) - i(e.y+o.y)
//   F(f2) = (e.x-o.x) + i(e.y-o.y)
// -> 1 pk-fma per (k,h) covers both frequencies, Re+Im.
// ---------------------------------------------------------------------------
__launch_bounds__(64)
__global__ void kMain(const float* __restrict__ seq, const float* __restrict__ mu,
                      const float* __restrict__ stdv, const float* __restrict__ filt,
                      const int* __restrict__ lead, const int* __restrict__ shiftv,
                      const float* __restrict__ r, const float2* __restrict__ wT2,
                      const float* __restrict__ mbr, const float* __restrict__ mbi,
                      float* __restrict__ out) {
  __shared__ __align__(16) v4f rows4[17][48];   // rows[17][192]
  __shared__ v2f mix2[MIXJ_];                   // (mixr, mixi)
  __shared__ float zr_s[H2_];
  __shared__ float zi_s[H2_];

  int bc = blockIdx.x;
  int b = bc / C_;
  int c = bc - b * C_;
  int t = threadIdx.x;

  // ---- phase 1: gather 16 leader windows (+sign) and own yhn row into LDS
#pragma unroll 1
  for (int k = 0; k < 17; k++) {
    float sg;
    const float* src;
    if (k < K_) {
      int ld = lead[(size_t)bc * K_ + k];
      int sh = shiftv[(size_t)bc * K_ + k];
      float rv = r[(size_t)bc * K_ + k];
      sg = (rv > 0.f) ? 1.f : ((rv < 0.f) ? -1.f : 0.f);
      src = seq + ((size_t)b * C_ + ld) * SEQLEN_ + (L_ - sh);
    } else {
      sg = 1.f;
      src = seq + (size_t)bc * SEQLEN_ + L_;
    }
    float* drow = (float*)rows4[k];
#pragma unroll
    for (int pass = 0; pass < 3; pass++) drow[t + 64 * pass] = src[t + 64 * pass] * sg;
  }
  __syncthreads();

  bool act = t < 49;
  int f = t;
  int f2 = 96 - t;

  v2f acc_e[17], acc_o[17];
#pragma unroll
  for (int k = 0; k < 17; k++) { acc_e[k] = (v2f){0.f, 0.f}; acc_o[k] = (v2f){0.f, 0.f}; }

  if (act) {
    // ---- phase 2: DFT with positive-angle twiddles c=cos(w f h), s=sin(w f h)
    float step = (TWO_PI_F / 192.f) * (float)f;
    float cs1, sn1, cs2, sn2, cs3, sn3, cs4, sn4;
    sincosf(step, &sn1, &cs1);
    sincosf(2.f * step, &sn2, &cs2);
    sincosf(3.f * step, &sn3, &cs3);
    sincosf(4.f * step, &sn4, &cs4);
    v2f A1 = (v2f){cs1, sn1}, B1 = (v2f){-sn1, cs1};
    v2f A2 = (v2f){cs2, sn2}, B2 = (v2f){-sn2, cs2};
    v2f A3 = (v2f){cs3, sn3}, B3 = (v2f){-sn3, cs3};
    v2f A4 = (v2f){cs4, sn4}, B4 = (v2f){-sn4, cs4};

    float cr = 1.f, ci = 0.f;
    for (int hq = 0; hq < 48; hq++) {
      v2f d0 = (v2f){cr, ci};
      v2f d1 = cr * A1 + ci * B1;
      v2f d2 = cr * A2 + ci * B2;
      v2f d3 = cr * A3 + ci * B3;
      v2f dn = cr * A4 + ci * B4;
#pragma unroll
      for (int k = 0; k < 17; k++) {
        v4f v = rows4[k][hq];
        acc_e[k] += (v2f){v.x, v.x} * d0;
        acc_o[k] += (v2f){v.y, v.y} * d1;
        acc_e[k] += (v2f){v.z, v.z} * d2;
        acc_o[k] += (v2f){v.w, v.w} * d3;
      }
      cr = dn.x; ci = dn.y;
    }

    // ---- phase 3: filt combine for both f and f2
    const float* fb = filt + (size_t)bc * OUT_;
#pragma unroll 1
    for (int which = 0; which < 2; which++) {
      int ff = which ? f2 : f;
      float se = which ? -1.f : 1.f;    // o-sign
      float si = which ? 1.f : -1.f;    // imag sign
      float Fre[17], Fim[17];
#pragma unroll
      for (int k = 0; k < 17; k++) {
        Fre[k] = acc_e[k].x + se * acc_o[k].x;
        Fim[k] = si * (acc_e[k].y + se * acc_o[k].y);
      }
      float yfR = Fre[16], yfI = Fim[16];
      float S1r = 0.f, S1i = 0.f, S2r = 0.f, S2i = 0.f, sg2 = 0.f;
#pragma unroll
      for (int k = 0; k < K_; k++) {
        float g1 = fb[k * H2_ + ff];
        float g2 = fb[(K_ + k) * H2_ + ff];
        float g12 = g1 * g2;
        S1r = fmaf(Fre[k], g1, S1r);
        S1i = fmaf(Fim[k], g1, S1i);
        S2r = fmaf(Fre[k], g12, S2r);
        S2i = fmaf(Fim[k], g12, S2i);
        sg2 += g2;
      }
      S2r = fmaf(-yfR, sg2, S2r);
      S2i = fmaf(-yfI, sg2, S2i);
      float g3 = fb[32 * H2_ + ff];
      mix2[ff] = (v2f){S1r, S1i};
      mix2[H2_ + ff] = (v2f){S2r, S2i};
      mix2[2 * H2_ + ff] = (v2f){yfR * g3, yfI * g3};
    }
  }
  __syncthreads();

  // ---- phase 4: complex mix matmul for f and f2
  if (act) {
    float zfr = mbr[f], zfi = mbi[f];
    float zgr = mbr[f2], zgi = mbi[f2];
    const float2* wf = wT2 + f;
    const float2* wg = wT2 + f2;
#pragma unroll 4
    for (int j = 0; j < MIXJ_; j++) {
      v2f m2 = mix2[j];
      float2 a = wf[(size_t)j * H2_];
      float2 bb = wg[(size_t)j * H2_];
      zfr = fmaf(m2.x, a.x, fmaf(-m2.y, a.y, zfr));
      zfi = fmaf(m2.x, a.y, fmaf(m2.y, a.x, zfi));
      zgr = fmaf(m2.x, bb.x, fmaf(-m2.y, bb.y, zgr));
      zgi = fmaf(m2.x, bb.y, fmaf(m2.y, bb.x, zgi));
    }
    zr_s[f] = zfr;  zi_s[f] = zfi;
    zr_s[f2] = zgr; zi_s[f2] = zgi;
  }
  __syncthreads();

  // ---- phase 5: irfft with h/h+96 symmetry + epilogue + store
  float m = mu[bc], sd = stdv[bc];
  const float* yhn = (const float*)rows4[16];
#pragma unroll 1
  for (int pp = t; pp < 96; pp += 64) {
    int h = pp;
    float ang = (TWO_PI_F / 192.f) * (float)h;
    float cs, sn;
    sincosf(ang, &sn, &cs);
    float base = 0.5f * zr_s[0] + ((h & 1) ? -0.5f : 0.5f) * zr_s[96];
    float aE = 0.f, aO = 0.f;
    float cv = cs, sv = sn;   // f = 1
    for (int fq = 1; fq < 96; fq += 2) {
      aO = fmaf(zr_s[fq], cv, fmaf(-zi_s[fq], sv, aO));
      float nc = cv * cs - sv * sn;
      float ns = cv * sn + sv * cs;
      aE = fmaf(zr_s[fq + 1], nc, fmaf(-zi_s[fq + 1], ns, aE));
      cv = nc * cs - ns * sn;
      sv = nc * sn + ns * cs;
    }
    float y0 = (base + aE + aO) * (2.f / 192.f);
    float y1 = (base + aE - aO) * (2.f / 192.f);
    out[((size_t)b * H_ + h) * C_ + c] = fmaf(yhn[h] + y0, sd, m);
    out[((size_t)b * H_ + h + 96) * C_ + c] = fmaf(yhn[h + 96] + y1, sd, m);
  }
}

// ---------------------------------------------------------------------------
extern "C" void kernel_launch(void* const* d_in, const int* in_sizes, int n_in,
                              void* d_out, int out_size, void* d_ws, size_t ws_size,
                              hipStream_t stream) {
  const float* x           = (const float*)d_in[0];
  const float* y_hat       = (const float*)d_in[1];
  const int*   lead        = (const int*)d_in[2];
  const int*   shiftv      = (const int*)d_in[3];
  const float* r           = (const float*)d_in[4];
  const float* temperature = (const float*)d_in[5];
  const float* cls_w       = (const float*)d_in[6];
  const float* cls_bias    = (const float*)d_in[7];
  const float* basic_state = (const float*)d_in[8];
  const float* mh_w        = (const float*)d_in[9];
  const float* mh_b        = (const float*)d_in[10];
  const float* mwr         = (const float*)d_in[11];
  const float* mwi         = (const float*)d_in[12];
  const float* mbr         = (const float*)d_in[13];
  const float* mbi         = (const float*)d_in[14];
  float* out = (float*)d_out;
  float* ws  = (float*)d_ws;

  dim3 gPre(B_, (C_ + CT_ - 1) / CT_);
  kPre<<<gPre, 256, 0, stream>>>(x, y_hat, cls_w, cls_bias, basic_state, r,
                                 temperature, ws + OFF_MU, ws + OFF_STD,
                                 ws + OFF_P, ws + OFF_CF, ws + OFF_SEQ);

  kU<<<(BC_ * JD_ + 255) / 256, 256, 0, stream>>>(ws + OFF_P, ws + OFF_CF, ws + OFF_U);

  kPackMixW<<<(MIXJ_ * H2_ + 255) / 256, 256, 0, stream>>>(
      mwr, mwi, (float2*)(ws + OFF_WT2));

  dim3 gF((OUT_ + 255) / 256, (BC_ + 63) / 64);
  kFilt<<<gF, 256, 0, stream>>>(ws + OFF_U, mh_w, mh_b, ws + OFF_FILT);

  kMain<<<BC_, 64, 0, stream>>>(ws + OFF_SEQ, ws + OFF_MU, ws + OFF_STD,
                                ws + OFF_FILT, lead, shiftv, r,
                                (const float2*)(ws + OFF_WT2), mbr, mbi, out);
}

// Round 5
// 307.748 us; speedup vs baseline: 1.1832x; 1.0970x over previous
//
#include <hip/hip_runtime.h>
#include <math.h>

#define B_ 8
#define L_ 336
#define H_ 192
#define C_ 321
#define K_ 16
#define S_ 8
#define H2_ 97
#define OUT_ 3201
#define SEQLEN_ 528
#define BC_ (B_ * C_)
#define JD_ 136
#define MIXJ_ 291

typedef float v2f __attribute__((ext_vector_type(2)));
typedef float v4f __attribute__((ext_vector_type(4)));

static constexpr size_t OFF_SEQ  = 0;
static constexpr size_t OFF_MU   = OFF_SEQ + (size_t)BC_ * SEQLEN_;
static constexpr size_t OFF_STD  = OFF_MU + BC_;
static constexpr size_t OFF_U    = OFF_STD + BC_;
static constexpr size_t OFF_WT2  = (OFF_U + (size_t)BC_ * JD_ + 1) & ~(size_t)1;
static constexpr size_t OFF_FILT = OFF_WT2 + (size_t)2 * MIXJ_ * H2_;

#define TWO_PI_F 6.283185307179586f
#define CT_ 16   // c-tile for kPre

// ---------------------------------------------------------------------------
// kPre: instance-norm stats + cls softmax + corr_feat + U materialization +
// normalized seq transpose.  Block = (b, 16-c tile), 256 threads.
// ---------------------------------------------------------------------------
__launch_bounds__(256)
__global__ void kPre(const float* __restrict__ x, const float* __restrict__ y_hat,
                     const float* __restrict__ cls_w, const float* __restrict__ cls_bias,
                     const float* __restrict__ basic_state, const float* __restrict__ r,
                     const float* __restrict__ temperature,
                     float* __restrict__ mu, float* __restrict__ stdv,
                     float* __restrict__ U, float* __restrict__ seq) {
  __shared__ float part[16][10][CT_];
  __shared__ float smu[CT_], sistd[CT_];
  __shared__ float sp[CT_][S_];
  __shared__ float scf[CT_][K_];
  __shared__ float tile[CT_][68];

  int b = blockIdx.x;
  int cb = blockIdx.y * CT_;
  int i = threadIdx.x & (CT_ - 1);
  int j = threadIdx.x >> 4;          // 0..15
  int c = cb + i;
  bool cok = c < C_;

  float sum = 0.f, sumsq = 0.f;
  float a[S_];
#pragma unroll
  for (int s = 0; s < S_; s++) a[s] = 0.f;

  if (cok) {
    for (int l = j; l < L_; l += 16) {
      float v = x[((size_t)b * L_ + l) * C_ + c];
      sum += v;
      sumsq = fmaf(v, v, sumsq);
#pragma unroll
      for (int s = 0; s < S_; s++) a[s] = fmaf(v, cls_w[s * L_ + l], a[s]);
    }
  }
  part[j][0][i] = sum;
  part[j][1][i] = sumsq;
#pragma unroll
  for (int s = 0; s < S_; s++) part[j][2 + s][i] = a[s];
  __syncthreads();

  if (threadIdx.x < CT_ && cok) {
    float s0 = 0.f, s1 = 0.f, ac[S_];
#pragma unroll
    for (int s = 0; s < S_; s++) ac[s] = 0.f;
    for (int jj = 0; jj < 16; jj++) {
      s0 += part[jj][0][i];
      s1 += part[jj][1][i];
#pragma unroll
      for (int s = 0; s < S_; s++) ac[s] += part[jj][2 + s][i];
    }
    float m = s0 * (1.f / L_);
    float var = fmaxf(s1 * (1.f / L_) - m * m, 0.f);
    float sd = sqrtf(var + 1e-8f);
    float is = 1.f / sd;
    int bc = b * C_ + c;
    mu[bc] = m;
    stdv[bc] = sd;
    smu[i] = m;
    sistd[i] = is;

    float lg[S_], mx = -1e30f;
#pragma unroll
    for (int s = 0; s < S_; s++) {
      lg[s] = ac[s] + cls_bias[s] + basic_state[c * S_ + s];
      mx = fmaxf(mx, lg[s]);
    }
    float den = 0.f;
#pragma unroll
    for (int s = 0; s < S_; s++) { float e = expf(lg[s] - mx); lg[s] = e; den += e; }
    float iden = 1.f / den;
#pragma unroll
    for (int s = 0; s < S_; s++) sp[i][s] = lg[s] * iden;

    float it = 1.f / temperature[0];
    float aa[K_], am = it;
#pragma unroll
    for (int k = 0; k < K_; k++) {
      aa[k] = fabsf(r[(size_t)bc * K_ + k]) * it;
      am = fmaxf(am, aa[k]);
    }
    float den2 = expf(it - am);
#pragma unroll
    for (int k = 0; k < K_; k++) { float e = expf(aa[k] - am); aa[k] = e; den2 += e; }
    float iden2 = 1.f / den2;
#pragma unroll
    for (int k = 0; k < K_; k++) scf[i][k] = aa[k] * iden2;
  }
  __syncthreads();

  // U materialization: u[bc][j] = p[s(j)] * (t(j)<16 ? cf[t(j)] : 1)
  for (int idx = threadIdx.x; idx < CT_ * JD_; idx += 256) {
    int ci = idx / JD_;
    int jj = idx - ci * JD_;
    int s = jj / 17;
    int t = jj - s * 17;
    if (cb + ci < C_) {
      float v = sp[ci][s];
      if (t < K_) v *= scf[ci][t];
      U[((size_t)b * C_ + cb + ci) * JD_ + jj] = v;
    }
  }

  // transpose + normalize into seq
  for (int t0 = 0; t0 < SEQLEN_; t0 += 66) {
    for (int tt = j; tt < 66; tt += 16) {
      int t = t0 + tt;
      float v = 0.f;
      if (cok) {
        v = (t < L_) ? x[((size_t)b * L_ + t) * C_ + c]
                     : y_hat[((size_t)b * H_ + (t - L_)) * C_ + c];
        v = (v - smu[i]) * sistd[i];
      }
      tile[i][tt] = v;
    }
    __syncthreads();
    {
      int lane = threadIdx.x & 31;
      int grp = threadIdx.x >> 5;   // 8 groups of 32 lanes, 2 rows each
#pragma unroll
      for (int rr = 0; rr < 2; rr++) {
        int ri = grp * 2 + rr;
        int cc2 = cb + ri;
        if (cc2 < C_) {
          float* dst = seq + ((size_t)b * C_ + cc2) * SEQLEN_ + t0;
          for (int tt = lane; tt < 66; tt += 32) dst[tt] = tile[ri][tt];
        }
      }
    }
    __syncthreads();
  }
}

// ---------------------------------------------------------------------------
// kPackMixW: wT2[j*97+g] = (wr[g,j], wi[g,j])
// ---------------------------------------------------------------------------
__global__ void kPackMixW(const float* __restrict__ mwr, const float* __restrict__ mwi,
                          float2* __restrict__ wT2) {
  int idx = blockIdx.x * blockDim.x + threadIdx.x;
  if (idx >= MIXJ_ * H2_) return;
  int j = idx / H2_;
  int g = idx - j * H2_;
  wT2[idx] = make_float2(mwr[(size_t)g * MIXJ_ + j], mwi[(size_t)g * MIXJ_ + j]);
}

// ---------------------------------------------------------------------------
// kFilt: thread = o-column; W2 column in 136 VGPRs; u via wave-uniform scalar
// loads; 32 rows per block, 4 independent accumulators (dep chain 136 -> 34).
// ---------------------------------------------------------------------------
__launch_bounds__(256)
__global__ void kFilt(const float* __restrict__ U, const float* __restrict__ mh_w,
                      const float* __restrict__ mh_b, float* __restrict__ filt) {
  int o = blockIdx.x * 256 + threadIdx.x;
  bool ook = o < OUT_;
  int oc = ook ? o : (OUT_ - 1);

  float w[JD_];
#pragma unroll
  for (int s = 0; s < S_; s++) {
#pragma unroll
    for (int t = 0; t < 17; t++) {
      w[s * 17 + t] = (t < K_)
          ? mh_w[(size_t)s * (K_ * OUT_) + (size_t)t * OUT_ + oc]
          : mh_b[(size_t)s * OUT_ + oc];
    }
  }

  int mBase = blockIdx.y * 32;
#pragma unroll 1
  for (int mi = 0; mi < 32; mi++) {
    int m = mBase + mi;
    if (m >= BC_) break;
    const float* up = U + (size_t)m * JD_;   // wave-uniform -> s_load
    float a0 = 0.f, a1 = 0.f, a2 = 0.f, a3 = 0.f;
#pragma unroll
    for (int jj = 0; jj < 34; jj++) {
      a0 = fmaf(up[jj], w[jj], a0);
      a1 = fmaf(up[34 + jj], w[34 + jj], a1);
      a2 = fmaf(up[68 + jj], w[68 + jj], a2);
      a3 = fmaf(up[102 + jj], w[102 + jj], a3);
    }
    if (ook) filt[(size_t)m * OUT_ + o] = (a0 + a1) + (a2 + a3);
  }
}

// ---------------------------------------------------------------------------
// kMain: 256 threads = 2 bc per block, 2 waves per bc (k-split DFT).
// Per bc: LDS sF[3332] holds rows[17][192] during DFT, then is overlaid with
// F[2][17][98], then with mix2/zr/zi.  yhn kept separately for the epilogue.
// Wave w2 computes k = w2*8 .. w2*8+8 (k=8 duplicated, identical values).
// Lane t<49 computes f=t and f2=96-t via even/odd-h accumulators.
// ---------------------------------------------------------------------------
__launch_bounds__(256)
__global__ void kMain(const float* __restrict__ seq, const float* __restrict__ mu,
                      const float* __restrict__ stdv, const float* __restrict__ filt,
                      const int* __restrict__ lead, const int* __restrict__ shiftv,
                      const float* __restrict__ r, const float2* __restrict__ wT2,
                      const float* __restrict__ mbr, const float* __restrict__ mbi,
                      float* __restrict__ out) {
  __shared__ __align__(16) float sF[2][3332];
  __shared__ __align__(16) float yhn[2][192];

  int half = threadIdx.x >> 7;
  int t128 = threadIdx.x & 127;
  int w2 = (threadIdx.x >> 6) & 1;
  int lane = threadIdx.x & 63;
  int bc = blockIdx.x * 2 + half;
  int b = bc / C_;
  int c = bc - b * C_;
  float* sFb = sF[half];
  float* yh = yhn[half];

  // ---- phase 1: gather rows into LDS
#pragma unroll 1
  for (int k = 0; k < 17; k++) {
    float sg;
    const float* src;
    if (k < K_) {
      int ld = lead[(size_t)bc * K_ + k];
      int sh = shiftv[(size_t)bc * K_ + k];
      float rv = r[(size_t)bc * K_ + k];
      sg = (rv > 0.f) ? 1.f : ((rv < 0.f) ? -1.f : 0.f);
      src = seq + ((size_t)b * C_ + ld) * SEQLEN_ + (L_ - sh);
    } else {
      sg = 1.f;
      src = seq + (size_t)bc * SEQLEN_ + L_;
    }
    float* dst = sFb + k * 192;
    for (int h = t128; h < H_; h += 128) {
      float v = src[h] * sg;
      dst[h] = v;
      if (k == 16) yh[h] = v;
    }
  }
  __syncthreads();

  // ---- phase 2: DFT over this wave's 9 k-rows
  bool act = lane < 49;
  int f = lane, f2 = 96 - lane;
  int k0 = w2 * 8;
  v2f acc_e[9], acc_o[9];
#pragma unroll
  for (int kk = 0; kk < 9; kk++) { acc_e[kk] = (v2f){0.f, 0.f}; acc_o[kk] = (v2f){0.f, 0.f}; }

  if (act) {
    float step = (TWO_PI_F / 192.f) * (float)f;
    float cs1, sn1, cs2, sn2, cs3, sn3, cs4, sn4;
    sincosf(step, &sn1, &cs1);
    sincosf(2.f * step, &sn2, &cs2);
    sincosf(3.f * step, &sn3, &cs3);
    sincosf(4.f * step, &sn4, &cs4);
    v2f A1 = (v2f){cs1, sn1}, B1 = (v2f){-sn1, cs1};
    v2f A2 = (v2f){cs2, sn2}, B2 = (v2f){-sn2, cs2};
    v2f A3 = (v2f){cs3, sn3}, B3 = (v2f){-sn3, cs3};
    v2f A4 = (v2f){cs4, sn4}, B4 = (v2f){-sn4, cs4};

    float cr = 1.f, ci = 0.f;
    for (int hq = 0; hq < 48; hq++) {
      v2f d0 = (v2f){cr, ci};
      v2f d1 = cr * A1 + ci * B1;
      v2f d2 = cr * A2 + ci * B2;
      v2f d3 = cr * A3 + ci * B3;
      v2f dn = cr * A4 + ci * B4;
#pragma unroll
      for (int kk = 0; kk < 9; kk++) {
        v4f v = ((const v4f*)(sFb + (k0 + kk) * 192))[hq];
        acc_e[kk] += (v2f){v.x, v.x} * d0;
        acc_o[kk] += (v2f){v.y, v.y} * d1;
        acc_e[kk] += (v2f){v.z, v.z} * d2;
        acc_o[kk] += (v2f){v.w, v.w} * d3;
      }
      cr = dn.x; ci = dn.y;
    }
  }
  __syncthreads();   // (a) everyone done reading rows

  // ---- write F = [Fre[17][98] | Fim[17][98]] overlaid on sF
  if (act) {
#pragma unroll
    for (int kk = 0; kk < 9; kk++) {
      int k = k0 + kk;
      float ex = acc_e[kk].x, ox = acc_o[kk].x;
      float ey = acc_e[kk].y, oy = acc_o[kk].y;
      sFb[k * 98 + f]         = ex + ox;
      sFb[1666 + k * 98 + f]  = -(ey + oy);
      sFb[k * 98 + f2]        = ex - ox;
      sFb[1666 + k * 98 + f2] = ey - oy;
    }
  }
  __syncthreads();   // (b) F complete

  // ---- phase 3: filt combine, one f per lane (97 lanes)
  int ff = t128;
  bool fok = ff < H2_;
  float S1r = 0.f, S1i = 0.f, S2r = 0.f, S2i = 0.f, YgR = 0.f, YgI = 0.f;
  if (fok) {
    float Fre[17], Fim[17];
#pragma unroll
    for (int k = 0; k < 17; k++) {
      Fre[k] = sFb[k * 98 + ff];
      Fim[k] = sFb[1666 + k * 98 + ff];
    }
    const float* fb = filt + (size_t)bc * OUT_;
    float yfR = Fre[16], yfI = Fim[16];
    float sg2 = 0.f;
#pragma unroll
    for (int k = 0; k < K_; k++) {
      float g1 = fb[k * H2_ + ff];
      float g2 = fb[(K_ + k) * H2_ + ff];
      float g12 = g1 * g2;
      S1r = fmaf(Fre[k], g1, S1r);
      S1i = fmaf(Fim[k], g1, S1i);
      S2r = fmaf(Fre[k], g12, S2r);
      S2i = fmaf(Fim[k], g12, S2i);
      sg2 += g2;
    }
    S2r = fmaf(-yfR, sg2, S2r);
    S2i = fmaf(-yfI, sg2, S2i);
    float g3 = fb[32 * H2_ + ff];
    YgR = yfR * g3;
    YgI = yfI * g3;
  }
  __syncthreads();   // (c) F reads done; sF reusable

  v2f* mix2 = (v2f*)sFb;          // 291 v2f = 582 floats
  float* zr = sFb + 582;          // 97
  float* zi = sFb + 679;          // 97
  if (fok) {
    mix2[ff]           = (v2f){S1r, S1i};
    mix2[H2_ + ff]     = (v2f){S2r, S2i};
    mix2[2 * H2_ + ff] = (v2f){YgR, YgI};
  }
  __syncthreads();   // (d) mix2 complete

  // ---- phase 4: complex mix matmul, one f per lane
  if (fok) {
    float zfr = mbr[ff], zfi = mbi[ff];
    const float2* wf = wT2 + ff;
#pragma unroll 2
    for (int j = 0; j < MIXJ_ - 1; j += 2) {
      v4f mm = *(const v4f*)(mix2 + j);
      float2 a0 = wf[(size_t)j * H2_];
      float2 a1 = wf[(size_t)(j + 1) * H2_];
      zfr = fmaf(mm.x, a0.x, fmaf(-mm.y, a0.y, zfr));
      zfi = fmaf(mm.x, a0.y, fmaf(mm.y, a0.x, zfi));
      zfr = fmaf(mm.z, a1.x, fmaf(-mm.w, a1.y, zfr));
      zfi = fmaf(mm.z, a1.y, fmaf(mm.w, a1.x, zfi));
    }
    {
      int j = MIXJ_ - 1;
      v2f m2 = mix2[j];
      float2 a0 = wf[(size_t)j * H2_];
      zfr = fmaf(m2.x, a0.x, fmaf(-m2.y, a0.y, zfr));
      zfi = fmaf(m2.x, a0.y, fmaf(m2.y, a0.x, zfi));
    }
    zr[ff] = zfr;
    zi[ff] = zfi;
  }
  __syncthreads();   // (e) z complete

  // ---- phase 5: irfft pair (h, h+96) + epilogue + store
  if (t128 < 96) {
    int h = t128;
    float m = mu[bc], sd = stdv[bc];
    float ang = (TWO_PI_F / 192.f) * (float)h;
    float cs, sn;
    sincosf(ang, &sn, &cs);
    float base = 0.5f * zr[0] + ((h & 1) ? -0.5f : 0.5f) * zr[96];
    float aE = 0.f, aO = 0.f;
    float cv = cs, sv = sn;   // f = 1
    for (int fq = 1; fq < 96; fq += 2) {
      aO = fmaf(zr[fq], cv, fmaf(-zi[fq], sv, aO));
      float nc = cv * cs - sv * sn;
      float ns = cv * sn + sv * cs;
      aE = fmaf(zr[fq + 1], nc, fmaf(-zi[fq + 1], ns, aE));
      cv = nc * cs - ns * sn;
      sv = nc * sn + ns * cs;
    }
    float y0 = (base + aE + aO) * (2.f / 192.f);
    float y1 = (base + aE - aO) * (2.f / 192.f);
    out[((size_t)b * H_ + h) * C_ + c] = fmaf(yh[h] + y0, sd, m);
    out[((size_t)b * H_ + h + 96) * C_ + c] = fmaf(yh[h + 96] + y1, sd, m);
  }
}

// ---------------------------------------------------------------------------
extern "C" void kernel_launch(void* const* d_in, const int* in_sizes, int n_in,
                              void* d_out, int out_size, void* d_ws, size_t ws_size,
                              hipStream_t stream) {
  const float* x           = (const float*)d_in[0];
  const float* y_hat       = (const float*)d_in[1];
  const int*   lead        = (const int*)d_in[2];
  const int*   shiftv      = (const int*)d_in[3];
  const float* r           = (const float*)d_in[4];
  const float* temperature = (const float*)d_in[5];
  const float* cls_w       = (const float*)d_in[6];
  const float* cls_bias    = (const float*)d_in[7];
  const float* basic_state = (const float*)d_in[8];
  const float* mh_w        = (const float*)d_in[9];
  const float* mh_b        = (const float*)d_in[10];
  const float* mwr         = (const float*)d_in[11];
  const float* mwi         = (const float*)d_in[12];
  const float* mbr         = (const float*)d_in[13];
  const float* mbi         = (const float*)d_in[14];
  float* out = (float*)d_out;
  float* ws  = (float*)d_ws;

  dim3 gPre(B_, (C_ + CT_ - 1) / CT_);
  kPre<<<gPre, 256, 0, stream>>>(x, y_hat, cls_w, cls_bias, basic_state, r,
                                 temperature, ws + OFF_MU, ws + OFF_STD,
                                 ws + OFF_U, ws + OFF_SEQ);

  kPackMixW<<<(MIXJ_ * H2_ + 255) / 256, 256, 0, stream>>>(
      mwr, mwi, (float2*)(ws + OFF_WT2));

  dim3 gF((OUT_ + 255) / 256, (BC_ + 31) / 32);
  kFilt<<<gF, 256, 0, stream>>>(ws + OFF_U, mh_w, mh_b, ws + OFF_FILT);

  kMain<<<BC_ / 2, 256, 0, stream>>>(ws + OFF_SEQ, ws + OFF_MU, ws + OFF_STD,
                                     ws + OFF_FILT, lead, shiftv, r,
                                     (const float2*)(ws + OFF_WT2), mbr, mbi, out);
}